// Round 3
// baseline (253.997 us; speedup 1.0000x reference)
//
#include <hip/hip_runtime.h>
#include <hip/hip_bf16.h>
#include <cstdint>

// ============================================================================
// ScaledDotAttention: out = softmax((Q Wq^T + bq)(K Wk^T + bk)^T / 8) @ V
// B=8, N=4096, DK=512, DM=64.
// R3: invariant-pointer LDS addressing (imm offsets), SALU-bumped staging
//     bases, flag-gated rescale, exp2-domain softmax, cvt_pk P-pack.
// ============================================================================

#define DEVINL __device__ __forceinline__

using f32x4  = __attribute__((ext_vector_type(4)))  float;
using bf16x8 = __attribute__((ext_vector_type(8)))  short;
using bf16x4 = __attribute__((ext_vector_type(4)))  short;

constexpr int BATCH = 8;
constexpr int N     = 4096;
constexpr int DK    = 512;
constexpr int DM    = 64;
constexpr int KVB   = 64;
constexpr int QB    = 128;
constexpr int STEPS = N / KVB;       // 64

// log2(e)/8 folded into pq so scores are in exp2 domain
#define PQ_SCALE 0.18033688011112042f
#define DEFER_THR 11.5f

DEVINL short cvt_bf16(float x) {
  uint32_t u = __float_as_uint(x);
  uint32_t r = u + 0x7fffu + ((u >> 16) & 1u);
  return (short)(r >> 16);
}

DEVINL uint32_t cvtpk(float lo, float hi) {
  uint32_t r;
  asm("v_cvt_pk_bf16_f32 %0, %1, %2" : "=v"(r) : "v"(lo), "v"(hi));
  return r;
}

DEVINL void async16(void* lds, const void* g) {
  __builtin_amdgcn_global_load_lds(
      (const __attribute__((address_space(1))) uint32_t*)(uintptr_t)g,
      (__attribute__((address_space(3))) uint32_t*)(uint32_t)(uintptr_t)lds,
      16, 0, 0);
}

DEVINL f32x4 mfma16(bf16x8 a, bf16x8 b, f32x4 c) {
  return __builtin_amdgcn_mfma_f32_16x16x32_bf16(a, b, c, 0, 0, 0);
}

// ---------------------------------------------------------------------------
__global__ __launch_bounds__(256) void wconv_kernel(
    const float* __restrict__ Wk, const float* __restrict__ Wq,
    short* __restrict__ WkB, short* __restrict__ WqB) {
  int i = blockIdx.x * 256 + threadIdx.x;
  WkB[i] = cvt_bf16(Wk[i]);
  WqB[i] = cvt_bf16(Wq[i]);
}

// ---------------------------------------------------------------------------
__global__ __launch_bounds__(256) void vtrans_kernel(
    const float* __restrict__ V, short* __restrict__ Vt) {
  int bb = blockIdx.x;
  int b  = bb >> 9;
  int nt = (bb >> 3) & 63;
  int dt = bb & 7;
  int n0 = nt * 64, d0 = dt * 64;
  __shared__ short t_lds[64][80];
  int tid = threadIdx.x;
#pragma unroll
  for (int it = 0; it < 4; ++it) {
    int idx = it * 256 + tid;
    int row = idx >> 4;
    int c4  = idx & 15;
    f32x4 v = *(const f32x4*)&V[((size_t)b * N + n0 + row) * DK + d0 + c4 * 4];
#pragma unroll
    for (int j = 0; j < 4; ++j) t_lds[c4 * 4 + j][row] = cvt_bf16(v[j]);
  }
  __syncthreads();
#pragma unroll
  for (int it = 0; it < 2; ++it) {
    int idx = it * 256 + tid;
    int rd = idx >> 3;
    int ck = idx & 7;
    bf16x8 vv = *(const bf16x8*)&t_lds[rd][ck * 8];
    *(bf16x8*)&Vt[((size_t)b * DK + d0 + rd) * N + n0 + ck * 8] = vv;
  }
}

// ---------------------------------------------------------------------------
__global__ __launch_bounds__(512, 2) void proj_kernel(
    const float* __restrict__ Q, const float* __restrict__ K,
    const short* __restrict__ WqB, const short* __restrict__ WkB,
    const float* __restrict__ bq, const float* __restrict__ bk,
    short* __restrict__ pq, short* __restrict__ pk) {
  bool isK = blockIdx.x >= 256;
  const float* X    = isK ? K : Q;
  const short* W    = isK ? WkB : WqB;
  const float* bias = isK ? bk : bq;
  short* P          = isK ? pk : pq;
  float sc          = isK ? 1.0f : PQ_SCALE;
  int rb = (blockIdx.x & 255) * 128;

  __shared__ short x_lds[128 * 512];
  int tid = threadIdx.x, w = tid >> 6, lane = tid & 63, g = lane >> 4, c = lane & 15;

#pragma unroll
  for (int it = 0; it < 32; ++it) {
    int idx4 = it * 512 + tid;
    int row  = idx4 >> 7;
    int col  = (idx4 & 127) * 4;
    f32x4 v = *(const f32x4*)&X[((size_t)rb + row) * DK + col];
    bf16x4 hb;
#pragma unroll
    for (int j = 0; j < 4; ++j) hb[j] = cvt_bf16(v[j]);
    int scz = (col >> 3) ^ (row & 7);
    *(bf16x4*)&x_lds[row * 512 + scz * 8 + ((col >> 2) & 1) * 4] = hb;
  }
  __syncthreads();

  f32x4 o[4];
#pragma unroll
  for (int mt = 0; mt < 4; ++mt) o[mt] = f32x4{0.f, 0.f, 0.f, 0.f};
  int arow = w * 16 + c;
#pragma unroll
  for (int ks = 0; ks < 16; ++ks) {
    int scz = (ks * 4 + g) ^ (arow & 7);
    bf16x8 a = *(const bf16x8*)&x_lds[arow * 512 + scz * 8];
#pragma unroll
    for (int mt = 0; mt < 4; ++mt) {
      bf16x8 bfr = *(const bf16x8*)&W[(size_t)(mt * 16 + c) * DK + ks * 32 + g * 8];
      o[mt] = mfma16(a, bfr, o[mt]);
    }
  }
#pragma unroll
  for (int mt = 0; mt < 4; ++mt) {
    float bb = bias[mt * 16 + c];
#pragma unroll
    for (int r = 0; r < 4; ++r) {
      int row = rb + w * 16 + g * 4 + r;
      P[(size_t)row * DM + mt * 16 + c] = cvt_bf16((o[mt][r] + bb) * sc);
    }
  }
}

// ---------------------------------------------------------------------------
__global__ __launch_bounds__(512, 2) void flash_kernel(
    const short* __restrict__ pq, const short* __restrict__ pk,
    const short* __restrict__ vt, float* __restrict__ out) {
  int b  = blockIdx.x & 7;             // batch -> XCD (L2-local Vt)
  int qt = blockIdx.x >> 3;
  int q0 = qt * QB;

  int tid = threadIdx.x, w = tid >> 6, lane = tid & 63, g = lane >> 4, c = lane & 15;
  int qrow = w * 16 + c;
  int cs = c & 7;

  __shared__ short pk_lds[KVB * DM];            //  8KB
  __shared__ short vt_lds[2][DK * KVB];         // 128KB dbuf
  __shared__ short p_lds[QB * KVB];             // 16KB
  __shared__ float alpha_lds[QB];
  __shared__ float lsum_lds[QB];
  __shared__ unsigned long long aflag8;         // per-wave rescale flags

  // ------- invariant LDS read/write pointers (varying part -> imm offset) ---
  const short* pkr0 = pk_lds + c * 64 + ((g ^ cs) * 8);
  const short* pkr1 = pk_lds + c * 64 + (((4 + g) ^ cs) * 8);
  const short* pfr0 = p_lds + c * 64 + ((g ^ cs) * 8);
  const short* pfr1 = p_lds + c * 64 + (((4 + g) ^ cs) * 8);
  const short* vfA0 = &vt_lds[0][(w * 64 + c) * 64 + ((g ^ cs) * 8)];
  const short* vfA1 = &vt_lds[0][(w * 64 + c) * 64 + (((4 + g) ^ cs) * 8)];
  const short* vfB0 = vfA0 + DK * KVB;
  const short* vfB1 = vfA1 + DK * KVB;
  short* pw0 = p_lds + qrow * 64 + ((((g >> 1) + 0) ^ cs) * 8) + (g & 1) * 4;
  short* pw1 = p_lds + qrow * 64 + ((((g >> 1) + 2) ^ cs) * 8) + (g & 1) * 4;
  short* pw2 = p_lds + qrow * 64 + ((((g >> 1) + 4) ^ cs) * 8) + (g & 1) * 4;
  short* pw3 = p_lds + qrow * 64 + ((((g >> 1) + 6) ^ cs) * 8) + (g & 1) * 4;

  // ------- staging: uniform bases (SALU-bumped) + invariant lane voffsets ---
  const short* pk_base = pk + (size_t)b * N * DM;
  const short* vt_base = vt + (size_t)b * DK * N;
  int tr = tid >> 3, tc = tid & 7;
  int pk_vo = tr * 64 + ((tc ^ (tr & 7)) * 8);
  int vt_vo[8];
#pragma unroll
  for (int r = 0; r < 8; ++r)
    vt_vo[r] = (r * 64 + tr) * N + ((tc ^ (tr & 7)) * 8);
  short* pk_dst = pk_lds + w * 512;
  short* vt_dst0 = &vt_lds[0][w * 512];
  short* vt_dst1 = &vt_lds[1][w * 512];

  auto stage_pk = [&]() {
    async16((void*)pk_dst, (const void*)(pk_base + pk_vo));
    pk_base += KVB * DM;
  };
  auto stage_vt = [&](short* vdst) {
#pragma unroll
    for (int r = 0; r < 8; ++r)
      async16((void*)(vdst + r * 4096), (const void*)(vt_base + vt_vo[r]));
    vt_base += KVB;
  };

  // ------- pq fragments (registers) ----------------------------------------
  const short* pq_row = pq + ((size_t)b * N + q0 + qrow) * DM;
  bf16x8 qf0 = *(const bf16x8*)(pq_row + g * 8);
  bf16x8 qf1 = *(const bf16x8*)(pq_row + 32 + g * 8);

  f32x4 acc[4][8];
#pragma unroll
  for (int i = 0; i < 4; ++i)
#pragma unroll
    for (int j = 0; j < 8; ++j) acc[i][j] = f32x4{0.f, 0.f, 0.f, 0.f};

  float m_run = -1e30f, l_run = 0.f;
  float sv[16];
  uint32_t pbu[8];
  float alpha;

  // ========================= prolog =========================================
  stage_pk();
  stage_vt(vt_dst0);
  __syncthreads();

  {
#pragma unroll
    for (int s = 0; s < 4; ++s) {
      bf16x8 a0 = *(const bf16x8*)(pkr0 + s * 1024);
      bf16x8 a1 = *(const bf16x8*)(pkr1 + s * 1024);
      f32x4 d = f32x4{0.f, 0.f, 0.f, 0.f};
      d = mfma16(a0, qf0, d);
      d = mfma16(a1, qf1, d);
#pragma unroll
      for (int r = 0; r < 4; ++r) sv[s * 4 + r] = d[r];
    }
    float tmax = sv[0];
#pragma unroll
    for (int j = 1; j < 16; ++j) tmax = fmaxf(tmax, sv[j]);
    tmax = fmaxf(tmax, __shfl_xor(tmax, 16));
    tmax = fmaxf(tmax, __shfl_xor(tmax, 32));
    m_run = tmax;
    float ts = 0.f;
#pragma unroll
    for (int j = 0; j < 16; ++j) { sv[j] = exp2f(sv[j] - m_run); ts += sv[j]; }
    ts += __shfl_xor(ts, 16);
    ts += __shfl_xor(ts, 32);
    l_run = ts;
    alpha = 1.0f;
#pragma unroll
    for (int s = 0; s < 4; ++s) {
      pbu[s * 2]     = cvtpk(sv[s * 4 + 0], sv[s * 4 + 1]);
      pbu[s * 2 + 1] = cvtpk(sv[s * 4 + 2], sv[s * 4 + 3]);
    }
  }
  asm volatile("s_waitcnt lgkmcnt(0)" ::: "memory");
  __builtin_amdgcn_s_barrier();
  *(uint32_t*)pw0 = pbu[0]; *(uint32_t*)(pw0 + 2) = pbu[1];
  *(uint32_t*)pw1 = pbu[2]; *(uint32_t*)(pw1 + 2) = pbu[3];
  *(uint32_t*)pw2 = pbu[4]; *(uint32_t*)(pw2 + 2) = pbu[5];
  *(uint32_t*)pw3 = pbu[6]; *(uint32_t*)(pw3 + 2) = pbu[7];
  if (lane == 0) ((unsigned char*)&aflag8)[w] = 0;
  if (g == 0) alpha_lds[qrow] = 1.0f;
  stage_pk();
  asm volatile("s_waitcnt lgkmcnt(0)" ::: "memory");
  __builtin_amdgcn_s_barrier();
  __builtin_amdgcn_sched_barrier(0);

  // ========================= main loop ======================================
  for (int t = 0; t < STEPS - 1; ++t) {
    int vb = t & 1;
    stage_vt(vb ? vt_dst0 : vt_dst1);
    asm volatile("s_waitcnt vmcnt(8)" ::: "memory");   // vt(t) + pk(t+1) done
    __builtin_amdgcn_sched_barrier(0);

    // flag-gated rescale of acc (rare)
    {
      unsigned long long f = aflag8;
      if (f) {
        float al[8];
#pragma unroll
        for (int j = 0; j < 8; ++j) al[j] = alpha_lds[j * 16 + c];
#pragma unroll
        for (int i = 0; i < 4; ++i)
#pragma unroll
          for (int j = 0; j < 8; ++j) acc[i][j] *= al[j];
      }
    }

    // ---- QKT(t+1) ----
    __builtin_amdgcn_s_setprio(1);
#pragma unroll
    for (int s = 0; s < 4; ++s) {
      bf16x8 a0 = *(const bf16x8*)(pkr0 + s * 1024);
      bf16x8 a1 = *(const bf16x8*)(pkr1 + s * 1024);
      f32x4 d = f32x4{0.f, 0.f, 0.f, 0.f};
      d = mfma16(a0, qf0, d);
      d = mfma16(a1, qf1, d);
#pragma unroll
      for (int r = 0; r < 4; ++r) sv[s * 4 + r] = d[r];
    }
    __builtin_amdgcn_s_setprio(0);

    // ---- softmax p1: running max (defer-max) ----
    float tmax = fmaxf(fmaxf(fmaxf(sv[0], sv[1]), fmaxf(sv[2], sv[3])),
                       fmaxf(fmaxf(sv[4], sv[5]), fmaxf(sv[6], sv[7])));
    tmax = fmaxf(tmax, fmaxf(fmaxf(fmaxf(sv[8], sv[9]), fmaxf(sv[10], sv[11])),
                             fmaxf(fmaxf(sv[12], sv[13]), fmaxf(sv[14], sv[15]))));
    tmax = fmaxf(tmax, __shfl_xor(tmax, 16));
    tmax = fmaxf(tmax, __shfl_xor(tmax, 32));
    alpha = 1.0f;
    if (tmax > m_run + DEFER_THR) {
      alpha = exp2f(m_run - tmax);
      m_run = tmax;
    }

    // ---- PV(t) kh=0 ----
    const short* vf0 = vb ? vfB0 : vfA0;
    const short* vf1 = vb ? vfB1 : vfA1;
    __builtin_amdgcn_s_setprio(1);
    {
      bf16x8 pf[8];
#pragma unroll
      for (int j = 0; j < 8; ++j) pf[j] = *(const bf16x8*)(pfr0 + j * 1024);
#pragma unroll
      for (int i = 0; i < 4; ++i) {
        bf16x8 vfr = *(const bf16x8*)(vf0 + i * 1024);
#pragma unroll
        for (int j = 0; j < 8; ++j) acc[i][j] = mfma16(vfr, pf[j], acc[i][j]);
      }
    }
    __builtin_amdgcn_s_setprio(0);

    // ---- softmax p2: exp2 + partial sum ----
    float ts = 0.f;
#pragma unroll
    for (int j = 0; j < 16; ++j) { sv[j] = exp2f(sv[j] - m_run); ts += sv[j]; }

    // ---- PV(t) kh=1 ----
    __builtin_amdgcn_s_setprio(1);
    {
      bf16x8 pf[8];
#pragma unroll
      for (int j = 0; j < 8; ++j) pf[j] = *(const bf16x8*)(pfr1 + j * 1024);
#pragma unroll
      for (int i = 0; i < 4; ++i) {
        bf16x8 vfr = *(const bf16x8*)(vf1 + i * 1024);
#pragma unroll
        for (int j = 0; j < 8; ++j) acc[i][j] = mfma16(vfr, pf[j], acc[i][j]);
      }
    }
    __builtin_amdgcn_s_setprio(0);

    // ---- softmax p3: reduce + pack ----
    ts += __shfl_xor(ts, 16);
    ts += __shfl_xor(ts, 32);
    l_run = l_run * alpha + ts;
#pragma unroll
    for (int s = 0; s < 4; ++s) {
      pbu[s * 2]     = cvtpk(sv[s * 4 + 0], sv[s * 4 + 1]);
      pbu[s * 2 + 1] = cvtpk(sv[s * 4 + 2], sv[s * 4 + 3]);
    }

    asm volatile("s_waitcnt lgkmcnt(0)" ::: "memory");
    __builtin_amdgcn_s_barrier();
    __builtin_amdgcn_sched_barrier(0);

    // ---- region B: publish P(t+1), alpha, flag; stage pk(t+2) ----
    *(uint32_t*)pw0 = pbu[0]; *(uint32_t*)(pw0 + 2) = pbu[1];
    *(uint32_t*)pw1 = pbu[2]; *(uint32_t*)(pw1 + 2) = pbu[3];
    *(uint32_t*)pw2 = pbu[4]; *(uint32_t*)(pw2 + 2) = pbu[5];
    *(uint32_t*)pw3 = pbu[6]; *(uint32_t*)(pw3 + 2) = pbu[7];
    if (g == 0) alpha_lds[qrow] = alpha;
    {
      int any = __any(alpha != 1.0f);
      if (lane == 0) ((unsigned char*)&aflag8)[w] = (unsigned char)any;
    }
    if (t < STEPS - 2) stage_pk();
    asm volatile("s_waitcnt lgkmcnt(0)" ::: "memory");
    __builtin_amdgcn_s_barrier();
    __builtin_amdgcn_sched_barrier(0);
  }

  // ========================= epilog: PV(63) =================================
  asm volatile("s_waitcnt vmcnt(0)" ::: "memory");
  __builtin_amdgcn_sched_barrier(0);
  {
    unsigned long long f = aflag8;
    if (f) {
      float al[8];
#pragma unroll
      for (int j = 0; j < 8; ++j) al[j] = alpha_lds[j * 16 + c];
#pragma unroll
      for (int i = 0; i < 4; ++i)
#pragma unroll
        for (int j = 0; j < 8; ++j) acc[i][j] *= al[j];
    }
  }
  {
    int vb = (STEPS - 1) & 1;
    const short* vf0 = vb ? vfB0 : vfA0;
    const short* vf1 = vb ? vfB1 : vfA1;
    {
      bf16x8 pf[8];
#pragma unroll
      for (int j = 0; j < 8; ++j) pf[j] = *(const bf16x8*)(pfr0 + j * 1024);
#pragma unroll
      for (int i = 0; i < 4; ++i) {
        bf16x8 vfr = *(const bf16x8*)(vf0 + i * 1024);
#pragma unroll
        for (int j = 0; j < 8; ++j) acc[i][j] = mfma16(vfr, pf[j], acc[i][j]);
      }
    }
    {
      bf16x8 pf[8];
#pragma unroll
      for (int j = 0; j < 8; ++j) pf[j] = *(const bf16x8*)(pfr1 + j * 1024);
#pragma unroll
      for (int i = 0; i < 4; ++i) {
        bf16x8 vfr = *(const bf16x8*)(vf1 + i * 1024);
#pragma unroll
        for (int j = 0; j < 8; ++j) acc[i][j] = mfma16(vfr, pf[j], acc[i][j]);
      }
    }
  }

  if (g == 0) lsum_lds[qrow] = l_run;
  asm volatile("s_waitcnt lgkmcnt(0)" ::: "memory");
  __builtin_amdgcn_s_barrier();

  float* out_b = out + (size_t)b * N * DK;
#pragma unroll
  for (int j = 0; j < 8; ++j) {
    float rl = 1.f / lsum_lds[j * 16 + c];
    int q = q0 + j * 16 + c;
#pragma unroll
    for (int i = 0; i < 4; ++i) {
      f32x4 o = acc[i][j];
      o[0] *= rl; o[1] *= rl; o[2] *= rl; o[3] *= rl;
      *(f32x4*)&out_b[(size_t)q * DK + w * 64 + i * 16 + g * 4] = o;
    }
  }
}

// ---------------------------------------------------------------------------
extern "C" void kernel_launch(void* const* d_in, const int* in_sizes, int n_in,
                              void* d_out, int out_size, void* d_ws, size_t ws_size,
                              hipStream_t stream) {
  (void)in_sizes; (void)n_in; (void)out_size; (void)ws_size;
  const float* K  = (const float*)d_in[0];
  const float* Q  = (const float*)d_in[1];
  const float* V  = (const float*)d_in[2];
  const float* Wk = (const float*)d_in[3];
  const float* bk = (const float*)d_in[4];
  const float* Wq = (const float*)d_in[5];
  const float* bq = (const float*)d_in[6];
  float* out = (float*)d_out;

  char* ws = (char*)d_ws;
  short* pq  = (short*)(ws + 0);
  short* pk  = (short*)(ws + ((size_t)4 << 20));
  short* vt  = (short*)(ws + ((size_t)8 << 20));
  short* WqB = (short*)(ws + ((size_t)40 << 20));
  short* WkB = (short*)(ws + ((size_t)40 << 20) + 64 * 512 * 2);

  hipLaunchKernelGGL(wconv_kernel,  dim3(128),  dim3(256), 0, stream, Wk, Wq, WkB, WqB);
  hipLaunchKernelGGL(vtrans_kernel, dim3(4096), dim3(256), 0, stream, V, vt);
  hipLaunchKernelGGL(proj_kernel,   dim3(512),  dim3(512), 0, stream, Q, K, WqB, WkB, bq, bk, pq, pk);
  hipLaunchKernelGGL(flash_kernel,  dim3(256),  dim3(512), 0, stream, pq, pk, vt, out);
}